// Round 3
// baseline (172.377 us; speedup 1.0000x reference)
//
#include <hip/hip_runtime.h>

typedef __bf16 bf16x8 __attribute__((ext_vector_type(8)));
typedef float floatx4 __attribute__((ext_vector_type(4)));

#define XS 136  // LDS row stride in bf16 elements (272 B -> 2-way bank aliasing = free)

__device__ __forceinline__ unsigned short f32_bf16(float f) {
    union { float f; unsigned int u; } c; c.f = f;
    return (unsigned short)((c.u + 0x7fffu + ((c.u >> 16) & 1u)) >> 16);  // RNE, finite inputs
}

// w1 -> MFMA B-fragment order, with hidden-col mapping h(nt,l15) = l15*32 + nt
// (any bijection works since the epilogue reduces over all hidden cols; this one
//  makes the per-nt b1/w2 coefficients contiguous in nt -> float4 loads).
// frag f = (e*32+nt)*4+ks ; lane (quad,l15) holds B[k=quad*8+j][n=l15] = w1[e][h][k]
__global__ __launch_bounds__(256) void prep_w1_frag(const float* __restrict__ w1,
                                                    unsigned short* __restrict__ wbf) {
    int g    = blockIdx.x * 256 + threadIdx.x;   // 64 blocks -> 16384 threads
    int lane = g & 63;
    int frag = g >> 6;                            // 0..255
    int ks   = frag & 3;
    int nt   = (frag >> 2) & 31;
    int e    = frag >> 7;
    int l15  = lane & 15;
    int quad = lane >> 4;
    int h    = l15 * 32 + nt;
    const float* src = w1 + ((e * 512 + h) * 128 + ks * 32 + quad * 8);
    unsigned short* dst = wbf + (long)g * 8;      // 16 B/lane, contiguous per wave
    #pragma unroll
    for (int j = 0; j < 8; ++j) dst[j] = f32_bf16(src[j]);
}

// One workgroup = 64 rows x all 1024 columns (2 experts x 512 hidden).
// wave w: mh = w&1 -> rows mh*32..mh*32+31 (2 m-tiles), expert = w>>1.
// A fragments are register-resident (loaded from LDS exactly once).
__global__ __launch_bounds__(256, 4) void moe_fused(
    const float* __restrict__ x,
    const unsigned short* __restrict__ wbf,   // fragment-ordered bf16 w1
    const float* __restrict__ b1,             // [2][512]
    const float* __restrict__ w2,             // [2][2][512]
    const float* __restrict__ b2,             // [2][2]
    const float* __restrict__ protos,         // [2][128]
    float* __restrict__ out)                  // [B][2]
{
    __shared__ unsigned short xs[64 * XS];    // 17408 B
    __shared__ float out_s[64 * 4];           // [row][e][o]
    __shared__ int   t_s[64];

    const int tid  = threadIdx.x;
    const int lane = tid & 63;
    const int wave = tid >> 6;
    const int quad = lane >> 4;
    const int l15  = lane & 15;
    const int mh   = wave & 1;
    const int nh   = wave >> 1;               // expert index for this wave
    const long rowbase = (long)blockIdx.x * 64;

    // ---- routing: t = (d1 < d0) via sign of sum_c (p0-p1)*(0.5*(p0+p1)-x), fp64 ----
    // 4 threads per row, contiguous 32-element chunks -> float4 loads.
    {
        int r   = tid >> 2;
        int sub = tid & 3;
        const float* xr = x + (rowbase + r) * 128 + sub * 32;
        const float* p0 = protos + sub * 32;
        const float* p1 = protos + 128 + sub * 32;
        double acc = 0.0;
        #pragma unroll
        for (int k = 0; k < 8; ++k) {
            float4 xv = *(const float4*)(xr + k * 4);
            float4 a  = *(const float4*)(p0 + k * 4);
            float4 b  = *(const float4*)(p1 + k * 4);
            acc += ((double)a.x - b.x) * (0.5 * ((double)a.x + b.x) - xv.x);
            acc += ((double)a.y - b.y) * (0.5 * ((double)a.y + b.y) - xv.y);
            acc += ((double)a.z - b.z) * (0.5 * ((double)a.z + b.z) - xv.z);
            acc += ((double)a.w - b.w) * (0.5 * ((double)a.w + b.w) - xv.w);
        }
        acc += __shfl_xor(acc, 1);
        acc += __shfl_xor(acc, 2);
        if (sub == 0) t_s[r] = (acc > 0.0) ? 1 : 0;   // tie -> expert 0 (numpy argmin)
    }

    // ---- stage x tile: coalesced float4 global reads -> bf16 LDS ----
    for (int i = tid; i < 64 * 32; i += 256) {
        int r  = i >> 5;
        int c4 = (i & 31) * 4;
        float4 v = *(const float4*)(x + (rowbase + r) * 128 + c4);
        ushort4 p;
        p.x = f32_bf16(v.x); p.y = f32_bf16(v.y);
        p.z = f32_bf16(v.z); p.w = f32_bf16(v.w);
        *(ushort4*)&xs[r * XS + c4] = p;
    }
    __syncthreads();

    // ---- A fragments: 2 m-tiles x 4 k-steps, register-resident ----
    // A-operand layout: A[m = lane&15][k = quad*8 + j]
    bf16x8 afrag[2][4];
    #pragma unroll
    for (int mt = 0; mt < 2; ++mt) {
        int r = mh * 32 + mt * 16 + l15;
        #pragma unroll
        for (int ks = 0; ks < 4; ++ks)
            afrag[mt][ks] = *(const bf16x8*)&xs[r * XS + ks * 32 + quad * 8];
    }

    float outp[2][4][2] = {};   // [m-tile][reg(row)][o] layer-2 partials

    // ---- main loop: 32 n-tiles (this wave's expert), unrolled x4 ----
    const bf16x8* wb8 = (const bf16x8*)wbf + (long)nh * 32 * 4 * 64 + lane;
    const float*  b1p = b1 + nh * 512 + l15 * 32;
    const float*  w2ap = w2 + (nh * 2 + 0) * 512 + l15 * 32;
    const float*  w2bp = w2 + (nh * 2 + 1) * 512 + l15 * 32;
    for (int nt4 = 0; nt4 < 32; nt4 += 4) {
        float4 bbv  = *(const float4*)(b1p  + nt4);
        float4 w2av = *(const float4*)(w2ap + nt4);
        float4 w2bv = *(const float4*)(w2bp + nt4);
        #pragma unroll
        for (int u = 0; u < 4; ++u) {
            const bf16x8* wp = wb8 + (nt4 + u) * 256;
            bf16x8 bf0 = wp[0];
            bf16x8 bf1 = wp[64];
            bf16x8 bf2 = wp[128];
            bf16x8 bf3 = wp[192];
            float bb  = ((const float*)&bbv)[u];
            float w2a = ((const float*)&w2av)[u];
            float w2b = ((const float*)&w2bv)[u];
            #pragma unroll
            for (int mt = 0; mt < 2; ++mt) {
                floatx4 c = {bb, bb, bb, bb};   // bias folded into accumulator init
                c = __builtin_amdgcn_mfma_f32_16x16x32_bf16(afrag[mt][0], bf0, c, 0, 0, 0);
                c = __builtin_amdgcn_mfma_f32_16x16x32_bf16(afrag[mt][1], bf1, c, 0, 0, 0);
                c = __builtin_amdgcn_mfma_f32_16x16x32_bf16(afrag[mt][2], bf2, c, 0, 0, 0);
                c = __builtin_amdgcn_mfma_f32_16x16x32_bf16(afrag[mt][3], bf3, c, 0, 0, 0);
                #pragma unroll
                for (int rg = 0; rg < 4; ++rg) {
                    float h = fmaxf(c[rg], 0.0f);
                    outp[mt][rg][0] = fmaf(h, w2a, outp[mt][rg][0]);
                    outp[mt][rg][1] = fmaf(h, w2b, outp[mt][rg][1]);
                }
            }
        }
    }

    // ---- reduce layer-2 partials across the 16 column-lanes ----
    #pragma unroll
    for (int mt = 0; mt < 2; ++mt)
        #pragma unroll
        for (int rg = 0; rg < 4; ++rg)
            #pragma unroll
            for (int o = 0; o < 2; ++o) {
                float v = outp[mt][rg][o];
                v += __shfl_xor(v, 1);
                v += __shfl_xor(v, 2);
                v += __shfl_xor(v, 4);
                v += __shfl_xor(v, 8);
                outp[mt][rg][o] = v;
            }
    if (l15 == 0) {
        #pragma unroll
        for (int mt = 0; mt < 2; ++mt)
            #pragma unroll
            for (int rg = 0; rg < 4; ++rg) {
                int r = mh * 32 + mt * 16 + quad * 4 + rg;  // C/D: row = quad*4 + reg
                out_s[r * 4 + nh * 2 + 0] = outp[mt][rg][0];
                out_s[r * 4 + nh * 2 + 1] = outp[mt][rg][1];
            }
    }
    __syncthreads();

    // ---- select expert per row, add b2, coalesced store ----
    if (tid < 128) {
        int r  = tid >> 1;
        int o  = tid & 1;
        int te = t_s[r];
        out[(rowbase + r) * 2 + o] = out_s[r * 4 + te * 2 + o] + b2[te * 2 + o];
    }
}

extern "C" void kernel_launch(void* const* d_in, const int* in_sizes, int n_in,
                              void* d_out, int out_size, void* d_ws, size_t ws_size,
                              hipStream_t stream) {
    const float* x      = (const float*)d_in[0];
    const float* w1     = (const float*)d_in[1];
    const float* b1     = (const float*)d_in[2];
    const float* w2     = (const float*)d_in[3];
    const float* b2     = (const float*)d_in[4];
    const float* protos = (const float*)d_in[5];
    float* out = (float*)d_out;
    unsigned short* wbf = (unsigned short*)d_ws;   // 256 KiB bf16 fragment-ordered w1

    prep_w1_frag<<<dim3(64), dim3(256), 0, stream>>>(w1, wbf);
    moe_fused<<<dim3(2048), dim3(256), 0, stream>>>(x, wbf, b1, w2, b2, protos, out);
}

// Round 4
// 158.319 us; speedup vs baseline: 1.0888x; 1.0888x over previous
//
#include <hip/hip_runtime.h>

typedef __bf16 bf16x8 __attribute__((ext_vector_type(8)));
typedef float floatx4 __attribute__((ext_vector_type(4)));

#define XS 136  // LDS row stride in bf16 elements (272 B -> 2-way bank aliasing = free)

__device__ __forceinline__ unsigned short f32_bf16(float f) {
    union { float f; unsigned int u; } c; c.f = f;
    return (unsigned short)((c.u + 0x7fffu + ((c.u >> 16) & 1u)) >> 16);  // RNE, finite inputs
}

// w1 -> MFMA B-fragment order, hidden-col mapping h(nt,l15) = l15*32 + nt.
// frag f = (e*32+nt)*4+ks ; lane (quad,l15) holds B[k=quad*8+j][n=l15] = w1[e][h][k]
__global__ __launch_bounds__(256) void prep_w1_frag(const float* __restrict__ w1,
                                                    unsigned short* __restrict__ wbf) {
    int g    = blockIdx.x * 256 + threadIdx.x;   // 64 blocks -> 16384 threads
    int lane = g & 63;
    int frag = g >> 6;                            // 0..255
    int ks   = frag & 3;
    int nt   = (frag >> 2) & 31;
    int e    = frag >> 7;
    int l15  = lane & 15;
    int quad = lane >> 4;
    int h    = l15 * 32 + nt;
    const float* src = w1 + ((e * 512 + h) * 128 + ks * 32 + quad * 8);
    unsigned short* dst = wbf + (long)g * 8;      // 16 B/lane, contiguous per wave
    #pragma unroll
    for (int j = 0; j < 8; ++j) dst[j] = f32_bf16(src[j]);
}

// One workgroup = 128 rows x all 1024 hidden cols. Each weight fragment is read
// EXACTLY ONCE per block: wave w owns expert e = w>>1 and nt-half slice = w&1,
// and MFMAs its fragments against all 128 rows (8 register-resident m-tiles).
// Weight traffic: 1024 blocks x 256 KiB = 256 MiB (was 1 GiB in round 3).
__global__ __launch_bounds__(256, 2) void moe_fused(
    const float* __restrict__ x,
    const unsigned short* __restrict__ wbf,   // fragment-ordered bf16 w1
    const float* __restrict__ b1,             // [2][512]
    const float* __restrict__ w2,             // [2][2][512]
    const float* __restrict__ b2,             // [2][2]
    const float* __restrict__ protos,         // [2][128]
    float* __restrict__ out)                  // [B][2]
{
    __shared__ unsigned short xs[128 * XS];   // 34816 B
    __shared__ float out_s[2][128][2][2];     // [slice][row][e][o]  8192 B
    __shared__ int   t_s[128];                // 512 B   -> 43520 B total

    const int tid   = threadIdx.x;
    const int lane  = tid & 63;
    const int wave  = tid >> 6;
    const int quad  = lane >> 4;
    const int l15   = lane & 15;
    const int slice = wave & 1;               // nt-half 0/1
    const int e     = wave >> 1;              // expert
    const long rowbase = (long)blockIdx.x * 128;

    // ---- routing: t = (d1 < d0) via sign of sum_c (p0-p1)*(0.5*(p0+p1)-x), fp64 ----
    {
        int r   = tid >> 1;                   // 2 threads per row
        int sub = tid & 1;
        const float* xr = x + (rowbase + r) * 128 + sub * 64;
        const float* p0 = protos + sub * 64;
        const float* p1 = protos + 128 + sub * 64;
        double acc = 0.0;
        #pragma unroll
        for (int k = 0; k < 16; ++k) {
            float4 xv = *(const float4*)(xr + k * 4);
            float4 a  = *(const float4*)(p0 + k * 4);
            float4 b  = *(const float4*)(p1 + k * 4);
            acc += ((double)a.x - b.x) * (0.5 * ((double)a.x + b.x) - xv.x);
            acc += ((double)a.y - b.y) * (0.5 * ((double)a.y + b.y) - xv.y);
            acc += ((double)a.z - b.z) * (0.5 * ((double)a.z + b.z) - xv.z);
            acc += ((double)a.w - b.w) * (0.5 * ((double)a.w + b.w) - xv.w);
        }
        acc += __shfl_xor(acc, 1);
        if (sub == 0) t_s[r] = (acc > 0.0) ? 1 : 0;   // tie -> expert 0 (numpy argmin)
    }

    // ---- stage x tile: coalesced float4 global reads -> bf16 LDS ----
    for (int i = tid; i < 128 * 32; i += 256) {
        int r  = i >> 5;
        int c4 = (i & 31) * 4;
        float4 v = *(const float4*)(x + (rowbase + r) * 128 + c4);
        ushort4 p;
        p.x = f32_bf16(v.x); p.y = f32_bf16(v.y);
        p.z = f32_bf16(v.z); p.w = f32_bf16(v.w);
        *(ushort4*)&xs[r * XS + c4] = p;
    }
    __syncthreads();

    // ---- A fragments: 8 m-tiles x 4 k-steps, register-resident (one-time LDS read) ----
    // A-operand layout: A[m = lane&15][k = quad*8 + j]
    bf16x8 afrag[8][4];
    #pragma unroll
    for (int mt = 0; mt < 8; ++mt) {
        int r = mt * 16 + l15;
        #pragma unroll
        for (int ks = 0; ks < 4; ++ks)
            afrag[mt][ks] = *(const bf16x8*)&xs[r * XS + ks * 32 + quad * 8];
    }

    float outp[8][4][2] = {};   // [m-tile][reg(row)][o] layer-2 partials

    // ---- main loop: 16 n-tiles (this wave's expert + nt-half), all frags read once ----
    const bf16x8* wb8 = (const bf16x8*)wbf + (long)((e * 32 + slice * 16) * 4) * 64 + lane;
    const int    coff = e * 512 + l15 * 32 + slice * 16;
    const float* b1p  = b1 + coff;
    const float* w2ap = w2 + e * 1024 + l15 * 32 + slice * 16;
    const float* w2bp = w2ap + 512;
    for (int nt = 0; nt < 16; ++nt) {
        const bf16x8* wp = wb8 + nt * 256;
        bf16x8 bf0 = wp[0];
        bf16x8 bf1 = wp[64];
        bf16x8 bf2 = wp[128];
        bf16x8 bf3 = wp[192];
        float bb  = b1p[nt];
        float w2a = w2ap[nt];
        float w2b = w2bp[nt];
        #pragma unroll
        for (int mt = 0; mt < 8; ++mt) {
            floatx4 c = {bb, bb, bb, bb};   // bias folded into accumulator init
            c = __builtin_amdgcn_mfma_f32_16x16x32_bf16(afrag[mt][0], bf0, c, 0, 0, 0);
            c = __builtin_amdgcn_mfma_f32_16x16x32_bf16(afrag[mt][1], bf1, c, 0, 0, 0);
            c = __builtin_amdgcn_mfma_f32_16x16x32_bf16(afrag[mt][2], bf2, c, 0, 0, 0);
            c = __builtin_amdgcn_mfma_f32_16x16x32_bf16(afrag[mt][3], bf3, c, 0, 0, 0);
            #pragma unroll
            for (int rg = 0; rg < 4; ++rg) {
                float h = fmaxf(c[rg], 0.0f);
                outp[mt][rg][0] = fmaf(h, w2a, outp[mt][rg][0]);
                outp[mt][rg][1] = fmaf(h, w2b, outp[mt][rg][1]);
            }
        }
    }

    // ---- reduce layer-2 partials across the 16 column-lanes, write slice buffer ----
    #pragma unroll
    for (int mt = 0; mt < 8; ++mt)
        #pragma unroll
        for (int rg = 0; rg < 4; ++rg) {
            float v0 = outp[mt][rg][0];
            float v1 = outp[mt][rg][1];
            v0 += __shfl_xor(v0, 1);  v1 += __shfl_xor(v1, 1);
            v0 += __shfl_xor(v0, 2);  v1 += __shfl_xor(v1, 2);
            v0 += __shfl_xor(v0, 4);  v1 += __shfl_xor(v1, 4);
            v0 += __shfl_xor(v0, 8);  v1 += __shfl_xor(v1, 8);
            if (l15 == 0) {
                int r = mt * 16 + quad * 4 + rg;   // C/D: row = quad*4 + reg
                out_s[slice][r][e][0] = v0;
                out_s[slice][r][e][1] = v1;
            }
        }
    __syncthreads();

    // ---- select expert per row, combine nt-halves, add b2, coalesced store ----
    {
        int r  = tid >> 1;
        int o  = tid & 1;
        int te = t_s[r];
        out[(rowbase + r) * 2 + o] =
            out_s[0][r][te][o] + out_s[1][r][te][o] + b2[te * 2 + o];
    }
}

extern "C" void kernel_launch(void* const* d_in, const int* in_sizes, int n_in,
                              void* d_out, int out_size, void* d_ws, size_t ws_size,
                              hipStream_t stream) {
    const float* x      = (const float*)d_in[0];
    const float* w1     = (const float*)d_in[1];
    const float* b1     = (const float*)d_in[2];
    const float* w2     = (const float*)d_in[3];
    const float* b2     = (const float*)d_in[4];
    const float* protos = (const float*)d_in[5];
    float* out = (float*)d_out;
    unsigned short* wbf = (unsigned short*)d_ws;   // 256 KiB bf16 fragment-ordered w1

    prep_w1_frag<<<dim3(64), dim3(256), 0, stream>>>(w1, wbf);
    moe_fused<<<dim3(1024), dim3(256), 0, stream>>>(x, wbf, b1, w2, b2, protos, out);
}